// Round 6
// baseline (493.709 us; speedup 1.0000x reference)
//
#include <hip/hip_runtime.h>
#include <hip/hip_fp16.h>
#include <math.h>

#define N_POS 8192
#define BATCH 4
#define N_GT 512
#define BG 2048
#define EPSV 1e-6f

#define KA_BLOCKS 2048
#define ROWS_A 4
#define KC_BLOCKS 512
#define ROWS_C 16

typedef float vf4 __attribute__((ext_vector_type(4)));

// workspace float offsets
// dpack: fp16 [8192][2048], column j = 8*t + k owned by thread t (batch = j>>9 = wave id)
#define WS_DPACK 0                                // 32 MiB of halves = 8M floats
#define WS_COLSUM (N_POS * BG / 2)                // [2048] atomic column sums
#define WS_MIND   (WS_COLSUM + BG)                // [4][8192] min_g D
#define WS_MAXP   (WS_MIND + BATCH * N_POS)       // [2048] kA block maxes
#define WS_SC     (WS_MAXP + KA_BLOCKS)           // [0]=maxd [1]=pmin [2]=prange [3..6]=n_est [7..10]=t1

// ---------------- kA: single pass over dis_matrix ----------------
// nt-loads stream dis through without polluting cache for dpack; gather gt cols -> fp16 dpack
__global__ __launch_bounds__(256) void whd_kA(const float* __restrict__ dis,
                                              const int* __restrict__ gt,
                                              float* __restrict__ wsf) {
    __shared__ __align__(16) float rowbuf[N_POS];   // 32 KB
    __shared__ unsigned short gtl[BG];              // 4 KB
    __shared__ float smax[4];
    const int t = threadIdx.x;
    const int wv = t >> 6, lane = t & 63;
    const int row0 = blockIdx.x * ROWS_A;
    __half* dpack = (__half*)(wsf + WS_DPACK);
    float* minD = wsf + WS_MIND;

    for (int i = t; i < BG; i += 256) gtl[i] = (unsigned short)gt[i];
    __syncthreads();
    int c[8];
    #pragma unroll
    for (int k = 0; k < 8; k++) c[k] = gtl[8 * t + k];

    float tmax = -INFINITY;
    for (int r = 0; r < ROWS_A; r++) {
        const int n = row0 + r;
        if (r > 0) __syncthreads();     // previous row's gathers complete before overwrite
        const vf4* src = (const vf4*)(dis + (size_t)n * N_POS);
        vf4* dstl = (vf4*)rowbuf;
        #pragma unroll
        for (int j = 0; j < N_POS / 4 / 256; j++) {
            int i = t + 256 * j;
            vf4 v = __builtin_nontemporal_load(&src[i]);
            tmax = fmaxf(tmax, fmaxf(fmaxf(v.x, v.y), fmaxf(v.z, v.w)));
            dstl[i] = v;
        }
        __syncthreads();
        float g0 = rowbuf[c[0]], g1 = rowbuf[c[1]], g2 = rowbuf[c[2]], g3 = rowbuf[c[3]];
        float g4 = rowbuf[c[4]], g5 = rowbuf[c[5]], g6 = rowbuf[c[6]], g7 = rowbuf[c[7]];
        union { float4 f4; __half h[8]; } u;
        u.h[0] = __float2half_rn(g0); u.h[1] = __float2half_rn(g1);
        u.h[2] = __float2half_rn(g2); u.h[3] = __float2half_rn(g3);
        u.h[4] = __float2half_rn(g4); u.h[5] = __float2half_rn(g5);
        u.h[6] = __float2half_rn(g6); u.h[7] = __float2half_rn(g7);
        *(float4*)(dpack + (size_t)n * BG + 8 * t) = u.f4;
        // per-wave (= per-batch) min over this wave's 512 columns (fp32 pre-conversion)
        float m = fminf(fminf(fminf(g0, g1), fminf(g2, g3)),
                        fminf(fminf(g4, g5), fminf(g6, g7)));
        #pragma unroll
        for (int off = 32; off; off >>= 1) m = fminf(m, __shfl_xor(m, off, 64));
        if (lane == 0) minD[wv * N_POS + n] = m;
    }
    #pragma unroll
    for (int off = 32; off; off >>= 1) tmax = fmaxf(tmax, __shfl_down(tmax, off, 64));
    if (lane == 0) smax[wv] = tmax;
    __syncthreads();
    if (t == 0)
        wsf[WS_MAXP + blockIdx.x] = fmaxf(fmaxf(smax[0], smax[1]), fmaxf(smax[2], smax[3]));
}

// ---------------- kB: finalize scalars + n_est/term1; zero colsum ----------------
__global__ __launch_bounds__(1024) void whd_kB(const float* __restrict__ prob,
                                               float* __restrict__ wsf) {
    __shared__ float red[1024];
    const int t = threadIdx.x;
    float m = -INFINITY;
    for (int i = t; i < KA_BLOCKS; i += 1024) m = fmaxf(m, wsf[WS_MAXP + i]);
    red[t] = m; __syncthreads();
    for (int s = 512; s; s >>= 1) { if (t < s) red[t] = fmaxf(red[t], red[t + s]); __syncthreads(); }
    float maxdist = red[0]; __syncthreads();
    float lmin = INFINITY, lmax = -INFINITY;
    for (int i = t; i < BATCH * N_POS; i += 1024) {
        float v = prob[i];
        lmin = fminf(lmin, v); lmax = fmaxf(lmax, v);
    }
    red[t] = lmin; __syncthreads();
    for (int s = 512; s; s >>= 1) { if (t < s) red[t] = fminf(red[t], red[t + s]); __syncthreads(); }
    float pmin = red[0]; __syncthreads();
    red[t] = lmax; __syncthreads();
    for (int s = 512; s; s >>= 1) { if (t < s) red[t] = fmaxf(red[t], red[t + s]); __syncthreads(); }
    float pmax = red[0]; __syncthreads();
    float invr = 1.0f / (pmax - pmin);
    const float* minD = wsf + WS_MIND;
    for (int b = 0; b < BATCH; b++) {
        float sp = 0.f, spm = 0.f;
        for (int i = t; i < N_POS; i += 1024) {
            float p = (prob[b * N_POS + i] - pmin) * invr;
            p = fminf(fmaxf(p, 0.f), 1.f);
            sp += p;
            spm += p * minD[b * N_POS + i];
        }
        red[t] = sp; __syncthreads();
        for (int s = 512; s; s >>= 1) { if (t < s) red[t] += red[t + s]; __syncthreads(); }
        if (t == 0) wsf[WS_SC + 3 + b] = red[0];
        __syncthreads();
        red[t] = spm; __syncthreads();
        for (int s = 512; s; s >>= 1) { if (t < s) red[t] += red[t + s]; __syncthreads(); }
        if (t == 0) wsf[WS_SC + 7 + b] = red[0];
        __syncthreads();
    }
    if (t == 0) {
        wsf[WS_SC + 0] = maxdist;
        wsf[WS_SC + 1] = pmin;
        wsf[WS_SC + 2] = pmax - pmin;
    }
    for (int i = t; i < BG; i += 1024) wsf[WS_COLSUM + i] = 0.f;  // ws is poisoned 0xAA
}

// ---------------- kC: reciprocal pass over fp16 packed columns -> atomic colsum ----------------
__global__ __launch_bounds__(256) void whd_kC(const float* __restrict__ prob,
                                              float* __restrict__ wsf) {
    const int t = threadIdx.x;
    const int wv = t >> 6;              // batch of all 8 owned columns
    const int row0 = blockIdx.x * ROWS_C;
    const __half* dpack = (const __half*)(wsf + WS_DPACK);
    const float maxd = wsf[WS_SC + 0];
    const float pmin = wsf[WS_SC + 1];
    const float invr = 1.0f / wsf[WS_SC + 2];
    float acc[8];
    #pragma unroll
    for (int k = 0; k < 8; k++) acc[k] = 0.f;
    #pragma unroll
    for (int r = 0; r < ROWS_C; r++) {
        const int n = row0 + r;
        float p = (prob[wv * N_POS + n] - pmin) * invr;
        p = fminf(fmaxf(p, 0.f), 1.f);
        union { float4 f4; __half h[8]; } u;
        u.f4 = *(const float4*)(dpack + (size_t)n * BG + 8 * t);
        #pragma unroll
        for (int k = 0; k < 8; k++) {
            float d = __half2float(u.h[k]);
            acc[k] += 1.0f / (fmaf(p, d - maxd, maxd) + EPSV);
        }
    }
    float* colsum = wsf + WS_COLSUM;
    #pragma unroll
    for (int k = 0; k < 8; k++) atomicAdd(&colsum[8 * t + k], acc[k]);
}

// ---------------- kE: final scalar ----------------
__global__ __launch_bounds__(256) void whd_kE(const float* __restrict__ wsf,
                                              float* __restrict__ out) {
    __shared__ float red[256];
    const int t = threadIdx.x;
    float s = 0.f;
    for (int i = t; i < BG; i += 256) s += (float)N_POS / wsf[WS_COLSUM + i];
    red[t] = s; __syncthreads();
    for (int st = 128; st; st >>= 1) { if (t < st) red[t] += red[t + st]; __syncthreads(); }
    if (t == 0) {
        float term2 = red[0] * (1.0f / BG);
        float term1 = 0.f;
        for (int b = 0; b < BATCH; b++)
            term1 += wsf[WS_SC + 7 + b] / (wsf[WS_SC + 3 + b] + EPSV);
        term1 *= (1.0f / BATCH);
        out[0] = term1 + term2;
    }
}

extern "C" void kernel_launch(void* const* d_in, const int* in_sizes, int n_in,
                              void* d_out, int out_size, void* d_ws, size_t ws_size,
                              hipStream_t stream) {
    const float* prob = (const float*)d_in[0];   // (4, 8192) fp32
    const int* gt = (const int*)d_in[1];         // (4, 512) int32
    const float* dis = (const float*)d_in[2];    // (8192, 8192) fp32
    float* out = (float*)d_out;
    float* wsf = (float*)d_ws;

    whd_kA<<<KA_BLOCKS, 256, 0, stream>>>(dis, gt, wsf);
    whd_kB<<<1, 1024, 0, stream>>>(prob, wsf);
    whd_kC<<<KC_BLOCKS, 256, 0, stream>>>(prob, wsf);
    whd_kE<<<1, 256, 0, stream>>>(wsf, out);
}